// Round 3
// baseline (409.543 us; speedup 1.0000x reference)
//
#include <hip/hip_runtime.h>

// Problem constants
#define B_   4
#define NQ_  2048
#define NKV_ 2048
#define H_   16
#define DK_  64
#define DM_  1024
#define DKV_ 2048   // stacked K|V projection width

typedef _Float16 f16x8 __attribute__((ext_vector_type(8)));
typedef _Float16 f16x4 __attribute__((ext_vector_type(4)));
typedef float    f32x4 __attribute__((ext_vector_type(4)));

__device__ __forceinline__ void gload_lds16(const void* g, void* l) {
  __builtin_amdgcn_global_load_lds(
      (const __attribute__((address_space(1))) unsigned int*)g,
      (__attribute__((address_space(3))) unsigned int*)l, 16, 0, 0);
}

// ---------------- cast f32 -> f16 (4 elems/thread) ----------------
__global__ __launch_bounds__(256) void cast_f16(const float* __restrict__ in,
                                                _Float16* __restrict__ out, int n4) {
  int i = blockIdx.x * 256 + threadIdx.x;
  if (i >= n4) return;
  float4 v = ((const float4*)in)[i];
  f16x4 o = {(_Float16)v.x, (_Float16)v.y, (_Float16)v.z, (_Float16)v.w};
  *(f16x4*)(out + (size_t)i * 4) = o;
}

// ---------------- W [K][N] f32 -> Wt [N][K] f16 ----------------
__global__ __launch_bounds__(256) void wtrans(const float* __restrict__ W,
                                              _Float16* __restrict__ Wt) {
  __shared__ float tile[32][33];
  int bx = blockIdx.x & 31, by = blockIdx.x >> 5;
  int tx = threadIdx.x & 31, ty = threadIdx.x >> 5;  // ty 0..7
#pragma unroll
  for (int j = 0; j < 4; ++j)
    tile[ty + j * 8][tx] = W[(size_t)(by * 32 + ty + j * 8) * 1024 + bx * 32 + tx];
  __syncthreads();
#pragma unroll
  for (int j = 0; j < 4; ++j)
    Wt[(size_t)(bx * 32 + ty + j * 8) * 1024 + by * 32 + tx] = (_Float16)tile[tx][ty + j * 8];
}

// ---------------- GEMM: C[M][N] = A[M][K] @ Bt[N][K]^T (m97 structure) ----------------
template <int F32OUT>
__global__ __launch_bounds__(256, 2) void gemm_bt(const _Float16* __restrict__ A,
                                                  const _Float16* __restrict__ Bt,
                                                  void* __restrict__ Cp,
                                                  int M, int N, int K) {
  __shared__ _Float16 As[128 * 32];
  __shared__ _Float16 Bs[128 * 32];
  const int nbn = N >> 7;
  const int bm = blockIdx.x / nbn, bn = blockIdx.x % nbn;
  const int t = threadIdx.x, w = t >> 6, l = t & 63;
  const int lr = l & 15, lg = l >> 4;
  const int wr = w >> 1, wc = w & 1;
  const int m0 = bm << 7, n0 = bn << 7;

  f32x4 acc[4][4] = {};

  for (int k0 = 0; k0 < K; k0 += 32) {
#pragma unroll
    for (int p = 0; p < 2; ++p) {
      int off = p * 4096 + w * 1024 + l * 16;  // linear byte offset in 8KB tile
      int row = off >> 6;                       // 64B per row (32 f16)
      int col = (off & 63) >> 1;                // element col
      gload_lds16(A  + (size_t)(m0 + row) * K + k0 + col, (char*)As + p * 4096 + w * 1024);
      gload_lds16(Bt + (size_t)(n0 + row) * K + k0 + col, (char*)Bs + p * 4096 + w * 1024);
    }
    __syncthreads();
    f16x8 af[4], bq[4];
#pragma unroll
    for (int i = 0; i < 4; ++i) {
      af[i] = *(const f16x8*)((const char*)As + (wr * 64 + i * 16 + lr) * 64 + lg * 16);
      bq[i] = *(const f16x8*)((const char*)Bs + (wc * 64 + i * 16 + lr) * 64 + lg * 16);
    }
#pragma unroll
    for (int i = 0; i < 4; ++i)
#pragma unroll
      for (int j = 0; j < 4; ++j)
        acc[i][j] = __builtin_amdgcn_mfma_f32_16x16x32_f16(af[i], bq[j], acc[i][j], 0, 0, 0);
    __syncthreads();
  }
#pragma unroll
  for (int i = 0; i < 4; ++i)
#pragma unroll
    for (int j = 0; j < 4; ++j)
#pragma unroll
      for (int r = 0; r < 4; ++r) {
        size_t row = m0 + wr * 64 + i * 16 + lg * 4 + r;
        size_t col = n0 + wc * 64 + j * 16 + lr;
        if (F32OUT) ((float*)Cp)[row * N + col] = acc[i][j][r];
        else ((_Float16*)Cp)[row * N + col] = (_Float16)acc[i][j][r];
      }
}

// ---------------- V [b][kv][1024+h*64+d] -> Vt [b][h][d][kv] ----------------
__global__ __launch_bounds__(256) void vtrans(const _Float16* __restrict__ KVb,
                                              _Float16* __restrict__ Vt) {
  __shared__ _Float16 tile[64][72];  // [kv][d], padded rows (144B, 16B-aligned)
  int idx = blockIdx.x;
  int kt = idx & 31, h = (idx >> 5) & 15, b = idx >> 9;
  int kv0 = kt << 6;
  int t = threadIdx.x;
#pragma unroll
  for (int p = 0; p < 2; ++p) {
    int c = t + p * 256;
    int row = c >> 3, cb = (c & 7) * 16;
    f16x8 v = *(const f16x8*)(KVb + (size_t)(b * NKV_ + kv0 + row) * DKV_ + 1024 + h * 64 + cb / 2);
    *(f16x8*)((char*)&tile[row][0] + cb) = v;
  }
  __syncthreads();
  int d = t & 63, j0 = (t >> 6) * 2;
#pragma unroll
  for (int jj = 0; jj < 2; ++jj) {
    int kvs = (j0 + jj) * 8;
    f16x8 o;
#pragma unroll
    for (int u = 0; u < 8; ++u) o[u] = tile[kvs + u][d];
    *(f16x8*)(Vt + ((size_t)((b * H_ + h) * 64 + d)) * NKV_ + kv0 + kvs) = o;
  }
}

// ---------------- fused attention: softmax(Q K^T + bias) V ----------------
// block = 64 q-rows of one (b,h); 4 waves x 16 rows; KV tiles of 64.
__global__ __launch_bounds__(256, 2) void attn(const _Float16* __restrict__ Qb,
                                               const _Float16* __restrict__ KVb,
                                               const _Float16* __restrict__ Vt,
                                               const float* __restrict__ bias,
                                               _Float16* __restrict__ ctx) {
  __shared__ _Float16 Ks[64 * 64];      // [kv][d], XOR-swizzled rows
  __shared__ _Float16 Vs[64 * 64];      // [d][kv], XOR-swizzled rows
  __shared__ _Float16 Ps[4][16 * 64];   // per-wave P tile, XOR-swizzled
  int idx = blockIdx.x;
  int b = idx & 3, qt = (idx >> 2) & 31, h = idx >> 7;  // batch innermost: bias L2/L3 reuse
  int t = threadIdx.x, w = t >> 6, l = t & 63, lr = l & 15, lg = l >> 4;
  int qw = (qt << 6) + (w << 4);

  const _Float16* qp = Qb + (size_t)(b * NQ_ + qw + lr) * DM_ + h * 64 + lg * 8;
  f16x8 aq0 = *(const f16x8*)qp;
  f16x8 aq1 = *(const f16x8*)(qp + 32);

  f32x4 acc[4] = {};
  float mrow[4] = {-1e30f, -1e30f, -1e30f, -1e30f};
  float lsum[4] = {0.f, 0.f, 0.f, 0.f};

  const _Float16* Kbase = KVb + (size_t)b * NKV_ * DKV_ + h * 64;
  const _Float16* Vtb = Vt + (size_t)(b * H_ + h) * 64 * NKV_;
  const float* biasb = bias + ((size_t)h * NQ_ + qw + lg * 4) * NKV_;

  for (int kv0 = 0; kv0 < NKV_; kv0 += 64) {
    // ---- stage K tile [64 kv][64 d] and Vt tile [64 d][64 kv], swizzled ----
#pragma unroll
    for (int p = 0; p < 2; ++p) {
      int c = t + p * 256;
      int row = c >> 3, cb = (c & 7) * 16;
      f16x8 kd = *(const f16x8*)(Kbase + (size_t)(kv0 + row) * DKV_ + cb / 2);
      *(f16x8*)((char*)Ks + ((row * 128 + cb) ^ ((row & 7) << 4))) = kd;
      f16x8 vd = *(const f16x8*)(Vtb + (size_t)row * NKV_ + kv0 + cb / 2);
      *(f16x8*)((char*)Vs + ((row * 128 + cb) ^ ((row & 7) << 4))) = vd;
    }
    __syncthreads();

    // ---- bias prefetch (global latency hides under MFMA) ----
    float bv[4][4];
#pragma unroll
    for (int r = 0; r < 4; ++r) {
      const float* bp = biasb + (size_t)r * NKV_ + kv0 + lr;
#pragma unroll
      for (int nt = 0; nt < 4; ++nt) bv[nt][r] = bp[nt * 16];
    }

    // ---- S = Q K^T (f32 accum) ----
    f32x4 s[4];
#pragma unroll
    for (int nt = 0; nt < 4; ++nt) {
      int row = nt * 16 + lr;
      f16x8 kf0 = *(const f16x8*)((char*)Ks + ((row * 128 + lg * 16) ^ ((row & 7) << 4)));
      f16x8 kf1 = *(const f16x8*)((char*)Ks + ((row * 128 + 64 + lg * 16) ^ ((row & 7) << 4)));
      f32x4 z = {0.f, 0.f, 0.f, 0.f};
      z = __builtin_amdgcn_mfma_f32_16x16x32_f16(aq0, kf0, z, 0, 0, 0);
      s[nt] = __builtin_amdgcn_mfma_f32_16x16x32_f16(aq1, kf1, z, 0, 0, 0);
    }
#pragma unroll
    for (int nt = 0; nt < 4; ++nt)
#pragma unroll
      for (int r = 0; r < 4; ++r) s[nt][r] += bv[nt][r];

    // ---- online softmax (rows spread over 16-lane groups) ----
    float corr[4], mn[4];
#pragma unroll
    for (int r = 0; r < 4; ++r) {
      float v = fmaxf(fmaxf(s[0][r], s[1][r]), fmaxf(s[2][r], s[3][r]));
      v = fmaxf(v, __shfl_xor(v, 1));
      v = fmaxf(v, __shfl_xor(v, 2));
      v = fmaxf(v, __shfl_xor(v, 4));
      v = fmaxf(v, __shfl_xor(v, 8));
      mn[r] = fmaxf(mrow[r], v);
      corr[r] = __expf(mrow[r] - mn[r]);
      mrow[r] = mn[r];
    }
    float rs[4] = {0.f, 0.f, 0.f, 0.f};
#pragma unroll
    for (int nt = 0; nt < 4; ++nt)
#pragma unroll
      for (int r = 0; r < 4; ++r) {
        float p = __expf(s[nt][r] - mn[r]);
        s[nt][r] = p;
        rs[r] += p;
      }
#pragma unroll
    for (int r = 0; r < 4; ++r) {
      float v = rs[r];
      v += __shfl_xor(v, 1);
      v += __shfl_xor(v, 2);
      v += __shfl_xor(v, 4);
      v += __shfl_xor(v, 8);
      lsum[r] = lsum[r] * corr[r] + v;
    }
#pragma unroll
    for (int nt = 0; nt < 4; ++nt)
#pragma unroll
      for (int r = 0; r < 4; ++r) acc[nt][r] *= corr[r];

    // ---- P (C-layout) -> per-wave LDS -> A-fragment layout ----
#pragma unroll
    for (int r = 0; r < 4; ++r) {
      int row = lg * 4 + r;
#pragma unroll
      for (int nt = 0; nt < 4; ++nt)
        *(_Float16*)((char*)Ps[w] + ((row * 128 + (nt * 16 + lr) * 2) ^ ((row & 7) << 4))) =
            (_Float16)s[nt][r];
    }
    // ---- PV ----
#pragma unroll
    for (int kk = 0; kk < 2; ++kk) {
      f16x8 pa = *(const f16x8*)((char*)Ps[w] + ((lr * 128 + kk * 64 + lg * 16) ^ ((lr & 7) << 4)));
#pragma unroll
      for (int nt = 0; nt < 4; ++nt) {
        int row = nt * 16 + lr;
        f16x8 vf = *(const f16x8*)((char*)Vs + ((row * 128 + kk * 64 + lg * 16) ^ ((row & 7) << 4)));
        acc[nt] = __builtin_amdgcn_mfma_f32_16x16x32_f16(pa, vf, acc[nt], 0, 0, 0);
      }
    }
    __syncthreads();
  }

  // ---- normalize + write ctx[b][q][h*64+d] f16 ----
#pragma unroll
  for (int nt = 0; nt < 4; ++nt)
#pragma unroll
    for (int r = 0; r < 4; ++r) {
      float o = acc[nt][r] / lsum[r];
      size_t q = qw + lg * 4 + r;
      ctx[((size_t)b * NQ_ + q) * DM_ + h * 64 + nt * 16 + lr] = (_Float16)o;
    }
}

extern "C" void kernel_launch(void* const* d_in, const int* in_sizes, int n_in,
                              void* d_out, int out_size, void* d_ws, size_t ws_size,
                              hipStream_t stream) {
  const float* x    = (const float*)d_in[0];
  const float* enc  = (const float*)d_in[1];
  const float* bias = (const float*)d_in[2];
  const float* Wq   = (const float*)d_in[3];
  const float* Wk   = (const float*)d_in[4];
  const float* Wv   = (const float*)d_in[5];
  const float* Wo   = (const float*)d_in[6];
  char* ws = (char*)d_ws;
  const size_t MiB = 1024 * 1024;
  _Float16* WqT   = (_Float16*)(ws + 0 * MiB);
  _Float16* WkT   = (_Float16*)(ws + 2 * MiB);   // WkT+WvT contiguous: stacked Bt [2048][1024]
  _Float16* WvT   = (_Float16*)(ws + 4 * MiB);
  _Float16* WoT   = (_Float16*)(ws + 6 * MiB);
  _Float16* xf    = (_Float16*)(ws + 8 * MiB);
  _Float16* encf  = (_Float16*)(ws + 24 * MiB);
  _Float16* Qb    = (_Float16*)(ws + 40 * MiB);
  _Float16* KVb   = (_Float16*)(ws + 56 * MiB);  // [8192][2048]: cols 0..1023=K, 1024..2047=V
  _Float16* Vt    = (_Float16*)(ws + 88 * MiB);  // [B][H][64][NKV]
  _Float16* ctxf  = (_Float16*)(ws + 104 * MiB); // [8192][1024]

  wtrans<<<1024, 256, 0, stream>>>(Wq, WqT);
  wtrans<<<1024, 256, 0, stream>>>(Wk, WkT);
  wtrans<<<1024, 256, 0, stream>>>(Wv, WvT);
  wtrans<<<1024, 256, 0, stream>>>(Wo, WoT);
  cast_f16<<<8192, 256, 0, stream>>>(x, xf, 2097152);
  cast_f16<<<8192, 256, 0, stream>>>(enc, encf, 2097152);
  gemm_bt<0><<<512, 256, 0, stream>>>(xf, WqT, Qb, 8192, 1024, 1024);
  gemm_bt<0><<<1024, 256, 0, stream>>>(encf, WkT, KVb, 8192, 2048, 1024);
  vtrans<<<2048, 256, 0, stream>>>(KVb, Vt);
  attn<<<2048, 256, 0, stream>>>(Qb, KVb, Vt, bias, ctxf);
  gemm_bt<1><<<512, 256, 0, stream>>>(ctxf, WoT, d_out, 8192, 1024, 1024);
}